// Round 9
// baseline (557.981 us; speedup 1.0000x reference)
//
#include <hip/hip_runtime.h>
#include <math.h>

#define IN_DIM 128
#define H1 64
#define H2 32
#define NC 8
#define NB_MAX 512     // max buckets (n <= 131072)
#define BLK 512        // edge partition blocks
#define CAP 10240      // LDS staging capacity per bucket (entries; max bucket ~8.6K)

typedef unsigned int u32;

__device__ __forceinline__ float bf_lo(u32 u) { return __uint_as_float(u << 16); }
__device__ __forceinline__ float bf_hi(u32 u) { return __uint_as_float(u & 0xffff0000u); }
__device__ __forceinline__ unsigned short f2b(float f) {  // RNE float->bf16
  u32 u = __float_as_uint(f);
  u += 0x7fffu + ((u >> 16) & 1u);
  return (unsigned short)(u >> 16);
}

// ---------------- P1 (R22): bucket histogram + per-node degree ----------------
// bh for the partitioned counting sort; deg (global atomics, memset'd by host)
// lets dinv be computed before build -> unlocks proj1 fusion two stages early.

__global__ __launch_bounds__(256) void k_hist2(const int* __restrict__ dst,
                                               int* __restrict__ bh,
                                               int* __restrict__ deg,
                                               int E, int EPB, int NBk) {
  __shared__ int h[NB_MAX];
  int k = blockIdx.x, tid = threadIdx.x;
  for (int i = tid; i < NBk; i += 256) h[i] = 0;
  __syncthreads();
  int st = k * EPB, en = min(E, st + EPB);
  for (int i = st + tid; i < en; i += 256) {
    int d = dst[i];
    atomicAdd(&h[((u32)d) >> 8], 1);
    atomicAdd(&deg[d], 1);
  }
  __syncthreads();
  for (int b = tid; b < NBk; b += 256) bh[b * BLK + k] = h[b];
}

// ---------------- P2 (R22): fused scan + dinv (replaces 3 scan kernels) ----------------
// Block 0: monolithic exclusive scan of bh[L] -> S[L], S[L]=E (1024 threads,
// int4-vectorized chunks). Blocks >=1: dinv[i] = rsqrt(deg[i]+1) in parallel.

__global__ __launch_bounds__(1024) void k_scan_dinv(const int* __restrict__ A,
                                                    int* __restrict__ S,
                                                    const int* __restrict__ deg,
                                                    float* __restrict__ dinv,
                                                    int L, int n) {
  if (blockIdx.x == 0) {
    __shared__ int part[1024];
    int t = threadIdx.x;
    int C = (L + 1023) >> 10;        // per-thread chunk
    C = (C + 3) & ~3;                // multiple of 4 for int4
    int st = t * C, en = min(st + C, L);
    int s = 0;
    int i = st;
    for (; i + 3 < en; i += 4) {
      int4 v = *(const int4*)(A + i);
      s += v.x + v.y + v.z + v.w;
    }
    for (; i < en; ++i) s += A[i];
    part[t] = s;
    __syncthreads();
    for (int d = 1; d < 1024; d <<= 1) {
      int v = (t >= d) ? part[t - d] : 0;
      __syncthreads();
      part[t] += v;
      __syncthreads();
    }
    int base = (t == 0) ? 0 : part[t - 1];
    i = st;
    for (; i + 3 < en; i += 4) {
      int4 v = *(const int4*)(A + i);
      int4 o;
      o.x = base; o.y = base + v.x; o.z = o.y + v.y; o.w = o.z + v.z;
      *(int4*)(S + i) = o;
      base = o.w + v.w;
    }
    for (; i < en; ++i) { S[i] = base; base += A[i]; }
    if (t == 1023) S[L] = part[1023];
  } else {
    int i = (blockIdx.x - 1) * 1024 + threadIdx.x;
    if (i < n) dinv[i] = rsqrtf((float)(deg[i] + 1));  // +1 self-loop
  }
}

// ---------------- P3 (R22): fused scatter || proj1 (independent work, one launch) ----------------
// Blocks [0,BLK): bucket scatter (packed entry: dl<<17 | src).
// Blocks [BLK,...): proj1 h1p = bf16(dinv * (x @ W1^T)), 16 rows per block.

__global__ __launch_bounds__(256) void k_scat_proj(
    const int* __restrict__ src, const int* __restrict__ dst,
    const int* __restrict__ S, u32* __restrict__ packed,
    int E, int EPB, int NBk,
    const float4* __restrict__ x4, const float* __restrict__ W1,
    const float* __restrict__ dinv, unsigned short* __restrict__ h1p, int n) {
  __shared__ int cur[NB_MAX];          // scatter
  __shared__ float xs[16][IN_DIM];     // proj1
  __shared__ float wt[IN_DIM][H1 + 1]; // proj1
  int tid = threadIdx.x;

  if ((int)blockIdx.x < BLK) {
    int k = blockIdx.x;
    for (int b = tid; b < NBk; b += 256) cur[b] = S[b * BLK + k];
    __syncthreads();
    int st = k * EPB, en = min(E, st + EPB);
    for (int i = st + tid; i < en; i += 256) {
      int d = dst[i];
      int b = ((u32)d) >> 8;
      int pos = atomicAdd(&cur[b], 1);
      packed[pos] = (((u32)d & 255u) << 17) | (u32)src[i];
    }
    return;
  }

  int row0 = ((int)blockIdx.x - BLK) * 16;
  for (int i = tid; i < (H1 * IN_DIM / 4); i += 256) {
    float4 w = ((const float4*)W1)[i];
    int o = (i * 4) / IN_DIM;
    int k = (i * 4) % IN_DIM;
    wt[k + 0][o] = w.x; wt[k + 1][o] = w.y; wt[k + 2][o] = w.z; wt[k + 3][o] = w.w;
  }
  for (int i = tid; i < 16 * IN_DIM / 4; i += 256) {
    int r = (i * 4) / IN_DIM, k = (i * 4) % IN_DIM;
    int row = row0 + r;
    if (row < n)
      *((float4*)&xs[r][k]) = x4[(size_t)row * (IN_DIM / 4) + k / 4];
  }
  __syncthreads();

  int o = tid & 63, rq = tid >> 6;
  float a0 = 0.f, a1 = 0.f, a2 = 0.f, a3 = 0.f;
  for (int k = 0; k < IN_DIM; ++k) {
    float w = wt[k][o];
    a0 += xs[rq * 4 + 0][k] * w;
    a1 += xs[rq * 4 + 1][k] * w;
    a2 += xs[rq * 4 + 2][k] * w;
    a3 += xs[rq * 4 + 3][k] * w;
  }
  int r = row0 + rq * 4;
  if (r + 0 < n) h1p[(size_t)(r + 0) * H1 + o] = f2b(a0 * dinv[r + 0]);
  if (r + 1 < n) h1p[(size_t)(r + 1) * H1 + o] = f2b(a1 * dinv[r + 1]);
  if (r + 2 < n) h1p[(size_t)(r + 2) * H1 + o] = f2b(a2 * dinv[r + 2]);
  if (r + 3 < n) h1p[(size_t)(r + 3) * H1 + o] = f2b(a3 * dinv[r + 3]);
}

// ---------------- P4 (R21): per-bucket sort by (dst_local, src-tile) -> csr2 + off ----------------
// key = dl*8 | (src>>14): node segments contiguous (CSR via off[n+1]) and
// coarse-ascending in src (8 tiles) => gather kernels sweep src-space.

__global__ __launch_bounds__(256) void k_build3(const u32* __restrict__ packed,
                                                const int* __restrict__ S,
                                                u32* __restrict__ csr2,
                                                int* __restrict__ off,
                                                int n, int NBk) {
  __shared__ int bins[2048];
  __shared__ int cur[2048];
  __shared__ int scn[256];
  __shared__ u32 sbuf[CAP];  // 40 KB staging
  int b = blockIdx.x, tid = threadIdx.x;
  int r0 = S[b * BLK];
  int r1 = S[(b + 1) * BLK];  // last bucket: S[L] = E
  int m = r1 - r0;
  for (int i = tid; i < 2048; i += 256) bins[i] = 0;
  __syncthreads();
  for (int i = r0 + tid; i < r1; i += 256) {
    u32 p = packed[i];
    int key = (int)((p >> 17) << 3) | (int)((p & 0x1FFFFu) >> 14);
    atomicAdd(&bins[key], 1);
  }
  __syncthreads();
  int s = 0;
#pragma unroll
  for (int u = 0; u < 8; ++u) s += bins[tid * 8 + u];  // s = degree of dl=tid
  scn[tid] = s;
  __syncthreads();
  for (int d = 1; d < 256; d <<= 1) {
    int t = (tid >= d) ? scn[tid - d] : 0;
    __syncthreads();
    scn[tid] += t;
    __syncthreads();
  }
  int base = scn[tid] - s;  // exclusive start of dl=tid's 8 bins
  int node = b * 256 + tid;
  if (node < n) off[node] = r0 + base;
  if (b == NBk - 1 && tid == 0) off[n] = r1;
#pragma unroll
  for (int u = 0; u < 8; ++u) {
    int k = tid * 8 + u;
    cur[k] = base;
    base += bins[k];
  }
  __syncthreads();
  if (m <= CAP) {
    for (int i = r0 + tid; i < r1; i += 256) {
      u32 p = packed[i];
      int key = (int)((p >> 17) << 3) | (int)((p & 0x1FFFFu) >> 14);
      int pos = atomicAdd(&cur[key], 1);
      sbuf[pos] = p & 0x1FFFFu;
    }
    __syncthreads();
    for (int j = tid; j < m; j += 256)
      csr2[r0 + j] = sbuf[j];
  } else {
    for (int i = r0 + tid; i < r1; i += 256) {
      u32 p = packed[i];
      int key = (int)((p >> 17) << 3) | (int)((p & 0x1FFFFu) >> 14);
      int pos = atomicAdd(&cur[key], 1);
      csr2[r0 + pos] = p & 0x1FFFFu;
    }
  }
}

// ---------------- fused: layer-1 gather-agg + bias + relu + proj2 (R18/R5 best) ----------------
// TWO independent nodes per wave; one csr load carries 16 ids per node; each of
// the 4 gather instrs carries 4 edges of node0 + 4 of node1.

#define ACC8(v) do { \
    a0 += bf_lo((v).x); a1 += bf_hi((v).x); \
    a2 += bf_lo((v).y); a3 += bf_hi((v).y); \
    a4 += bf_lo((v).z); a5 += bf_hi((v).z); \
    a6 += bf_lo((v).w); a7 += bf_hi((v).w); } while (0)

#define RED8(m) do { \
    a0 += __shfl_xor(a0, m, 64); a1 += __shfl_xor(a1, m, 64); \
    a2 += __shfl_xor(a2, m, 64); a3 += __shfl_xor(a3, m, 64); \
    a4 += __shfl_xor(a4, m, 64); a5 += __shfl_xor(a5, m, 64); \
    a6 += __shfl_xor(a6, m, 64); a7 += __shfl_xor(a7, m, 64); } while (0)

__global__ __launch_bounds__(256) void k_agg64_proj2(
    const u32* __restrict__ hp,    // [n][32] packed bf16x2 (= [n][8] uint4)
    const float* __restrict__ dinv,
    const int* __restrict__ off, const int* __restrict__ csr,
    const float* __restrict__ b1, const float* __restrict__ W2,
    unsigned short* __restrict__ h2p, int n) {
  __shared__ float wt[H1][H2 + 1];   // W2 transposed: wt[k][o]
  __shared__ float rows[4][2][H1];   // relu(out1) rows, 2 nodes per wave
  __shared__ float b1s[H1];
  int tid = threadIdx.x;

  for (int i = tid; i < H2 * H1 / 4; i += 256) {
    float4 w = ((const float4*)W2)[i];
    int o = (i * 4) / H1, k = (i * 4) % H1;
    wt[k + 0][o] = w.x; wt[k + 1][o] = w.y; wt[k + 2][o] = w.z; wt[k + 3][o] = w.w;
  }
  if (tid < 16) ((float4*)b1s)[tid] = ((const float4*)b1)[tid];
  __syncthreads();

  int lane = tid & 63;
  int wv = __builtin_amdgcn_readfirstlane(tid >> 6);
  int p0n = (blockIdx.x * 4 + wv) * 2;       // first of this wave's 2 nodes
  int p0c = min(p0n, n - 1);
  int p1c = min(p0n + 1, n - 1);
  int g = lane >> 3, j = lane & 7;           // 8 groups of 8 lanes; lane j reads 16B
  int nh = g >> 2;                           // node-half of this group

  int tt = 0;
  if (lane < 3) tt = off[min(p0n + lane, n)];
  int r00 = __shfl(tt, 0, 64);
  int r01 = __shfl(tt, 1, 64);
  int r11 = __shfl(tt, 2, 64);
  float dv = 0.f;
  if (lane < 2) dv = dinv[min(p0n + lane, n - 1)];
  float d0 = __shfl(dv, 0, 64), d1 = __shfl(dv, 1, 64);

  const uint4* __restrict__ hp4 = (const uint4*)hp;
  float a0 = 0.f, a1 = 0.f, a2 = 0.f, a3 = 0.f,
        a4 = 0.f, a5 = 0.f, a6 = 0.f, a7 = 0.f;

  if ((g & 3) == 0) {  // self terms: group 0 -> node0, group 4 -> node1
    uint4 v = hp4[(size_t)(nh ? p1c : p0c) * (H1 / 8) + j];
    ACC8(v);
  }

  int mx = max(r01 - r00, r11 - r01);
  for (int kk = 0; kk * 16 < mx; ++kk) {
    int b0 = r00 + 16 * kk, b1e = r01 + 16 * kk;
    int ci = (lane < 32) ? min(b0 + (lane & 15), r01 - 1)
                         : min(b1e + (lane & 15), r11 - 1);
    int s = csr[max(ci, 0)];     // 16 ids per node, clamped coalesced load
#pragma unroll
    for (int it = 0; it < 4; ++it) {
      int e = it * 4 + (g & 3);
      int sv = __shfl(s, (nh ? 32 : 0) + e, 64);
      int eidx = (nh ? b1e : b0) + e;
      int lim = nh ? r11 : r01;
      if (eidx < lim) {
        uint4 v = hp4[(size_t)sv * (H1 / 8) + j];   // 4+4 edges / instruction
        ACC8(v);
      }
    }
  }
  RED8(8); RED8(16);  // reduce across the 4 groups of each node-half

  float d = (lane < 32) ? d0 : d1;
  if ((lane & 31) < 8) {   // lane j holds cols [8j, 8j+8) of its node
    int jj = lane & 7, nn = lane >> 5;
    float4 v0, v1;
    v0.x = fmaxf(a0 * d + b1s[8 * jj + 0], 0.f);
    v0.y = fmaxf(a1 * d + b1s[8 * jj + 1], 0.f);
    v0.z = fmaxf(a2 * d + b1s[8 * jj + 2], 0.f);
    v0.w = fmaxf(a3 * d + b1s[8 * jj + 3], 0.f);
    v1.x = fmaxf(a4 * d + b1s[8 * jj + 4], 0.f);
    v1.y = fmaxf(a5 * d + b1s[8 * jj + 5], 0.f);
    v1.z = fmaxf(a6 * d + b1s[8 * jj + 6], 0.f);
    v1.w = fmaxf(a7 * d + b1s[8 * jj + 7], 0.f);
    *(float4*)&rows[wv][nn][8 * jj + 0] = v0;
    *(float4*)&rows[wv][nn][8 * jj + 4] = v1;
  }
  __syncthreads();

  // proj2: lane -> (node = lane>>5, o = lane&31); full k loop, no final shfl
  int node = lane >> 5, o = lane & 31;
  float a = 0.f;
#pragma unroll
  for (int k = 0; k < H1; ++k) a += rows[wv][node][k] * wt[k][o];
  int wout = p0n + node;
  if (wout < n) h2p[(size_t)wout * H2 + o] = f2b(a * ((node) ? d1 : d0));
}

// ---------------- fused: layer-2 gather-agg + b2 + gates + leaf (R18/R5 best) ----------------

__global__ __launch_bounds__(256) void k_agg32_tree(
    const u32* __restrict__ hp,    // [n][16] packed bf16x2 (= [n][4] uint4)
    const float* __restrict__ dinv,
    const int* __restrict__ off, const int* __restrict__ csr,
    const float* __restrict__ b2, const float* __restrict__ gate_w,
    const float* __restrict__ gate_b, const float* __restrict__ leaf_w,
    float* __restrict__ out, int n) {
  __shared__ float gwt[H2][H2 + 1];  // gate_w transposed: gwt[k][j]
  __shared__ float lws[H2][NC + 1];
  __shared__ float rowh[4][2][H2];
  __shared__ float rowg[4][2][H2];
  __shared__ float b2s[H2];
  int tid = threadIdx.x;

  {
    float4 w = ((const float4*)gate_w)[tid];  // H2*H2/4 == 256
    int jj = (tid * 4) / H2, k = (tid * 4) % H2;
    gwt[k + 0][jj] = w.x; gwt[k + 1][jj] = w.y; gwt[k + 2][jj] = w.z; gwt[k + 3][jj] = w.w;
  }
  lws[tid >> 3][tid & 7] = leaf_w[tid];  // H2*NC == 256
  if (tid < 8) ((float4*)b2s)[tid] = ((const float4*)b2)[tid];
  __syncthreads();

  int lane = tid & 63;
  int wv = __builtin_amdgcn_readfirstlane(tid >> 6);
  int p0n = (blockIdx.x * 4 + wv) * 2;
  int p0c = min(p0n, n - 1);
  int p1c = min(p0n + 1, n - 1);
  int g = lane >> 2, j = lane & 3;   // 16 groups of 4 lanes
  int nh = g >> 3;                   // node-half of this group

  int tt = 0;
  if (lane < 3) tt = off[min(p0n + lane, n)];
  int r00 = __shfl(tt, 0, 64);
  int r01 = __shfl(tt, 1, 64);
  int r11 = __shfl(tt, 2, 64);
  float dv = 0.f;
  if (lane < 2) dv = dinv[min(p0n + lane, n - 1)];
  float d0 = __shfl(dv, 0, 64), d1 = __shfl(dv, 1, 64);

  const uint4* __restrict__ hp4 = (const uint4*)hp;
  float a0 = 0.f, a1 = 0.f, a2 = 0.f, a3 = 0.f,
        a4 = 0.f, a5 = 0.f, a6 = 0.f, a7 = 0.f;

  if ((g & 7) == 0) {  // self terms: group 0 -> node0, group 8 -> node1
    uint4 v = hp4[(size_t)(nh ? p1c : p0c) * (H2 / 8) + j];
    ACC8(v);
  }

  int mx = max(r01 - r00, r11 - r01);
  for (int kk = 0; kk * 16 < mx; ++kk) {
    int b0 = r00 + 16 * kk, b1e = r01 + 16 * kk;
    int ci = (lane < 32) ? min(b0 + (lane & 15), r01 - 1)
                         : min(b1e + (lane & 15), r11 - 1);
    int s = csr[max(ci, 0)];
#pragma unroll
    for (int it = 0; it < 2; ++it) {
      int e = it * 8 + (g & 7);
      int sv = __shfl(s, (nh ? 32 : 0) + e, 64);
      int eidx = (nh ? b1e : b0) + e;
      int lim = nh ? r11 : r01;
      if (eidx < lim) {
        uint4 v = hp4[(size_t)sv * (H2 / 8) + j];   // 8+8 edges / instruction
        ACC8(v);
      }
    }
  }
  RED8(4); RED8(8); RED8(16);  // reduce across the 8 groups of each node-half

  float d = (lane < 32) ? d0 : d1;
  if ((lane & 31) < 4) {   // lane j holds cols [8j, 8j+8) of its node
    int jj = lane & 3, nn = lane >> 5;
    float4 v0, v1;
    v0.x = a0 * d + b2s[8 * jj + 0];
    v0.y = a1 * d + b2s[8 * jj + 1];
    v0.z = a2 * d + b2s[8 * jj + 2];
    v0.w = a3 * d + b2s[8 * jj + 3];
    v1.x = a4 * d + b2s[8 * jj + 4];
    v1.y = a5 * d + b2s[8 * jj + 5];
    v1.z = a6 * d + b2s[8 * jj + 6];
    v1.w = a7 * d + b2s[8 * jj + 7];
    *(float4*)&rowh[wv][nn][8 * jj + 0] = v0;
    *(float4*)&rowh[wv][nn][8 * jj + 4] = v1;
  }
  __syncthreads();

  // gates: lane -> (node = lane>>5, f = lane&31); full k loop
  int node = lane >> 5, f = lane & 31;
  float gacc = 0.f;
#pragma unroll
  for (int k = 0; k < H2; ++k) gacc += rowh[wv][node][k] * gwt[k][f];
  rowg[wv][node][f] = 1.0f / (1.0f + __expf(-(gacc + gate_b[f])));
  __syncthreads();

  // leaf: within each 32-half, 4 groups of 8 lanes partial-sum then xor-reduce
  int c = lane & 7, gi = (lane >> 3) & 3;
  float a = 0.f;
#pragma unroll
  for (int j8 = 0; j8 < 8; ++j8) {
    int jj = gi * 8 + j8;
    a += rowg[wv][node][jj] * lws[jj][c];
  }
  a += __shfl_xor(a, 8, 64);
  a += __shfl_xor(a, 16, 64);
  int wout = p0n + node;
  if ((lane & 31) < 8 && wout < n) out[(size_t)wout * NC + c] = a;
}

// ---------------- host ----------------

static inline size_t align256(size_t x) { return (x + 255) & ~(size_t)255; }

extern "C" void kernel_launch(void* const* d_in, const int* in_sizes, int n_in,
                              void* d_out, int out_size, void* d_ws, size_t ws_size,
                              hipStream_t stream) {
  const float* x  = (const float*)d_in[0];
  const int*   ei = (const int*)d_in[1];
  const float* W1 = (const float*)d_in[2];
  const float* b1 = (const float*)d_in[3];
  const float* W2 = (const float*)d_in[4];
  const float* b2 = (const float*)d_in[5];
  const float* gw = (const float*)d_in[6];
  const float* gb = (const float*)d_in[7];
  const float* lw = (const float*)d_in[8];
  float* out = (float*)d_out;

  int n = in_sizes[0] / IN_DIM;
  int E = in_sizes[1] / 2;
  const int* src  = ei;
  const int* dstp = ei + E;

  int NBk = (n + 255) >> 8;                    // buckets of 256 nodes
  int EPB = (E + BLK - 1) / BLK;               // edges per partition block
  int L   = NBk * BLK;                         // blockhist entries

  // workspace layout: hot gather tables FIRST (256B-aligned; R17 straddle fix)
  char* w = (char*)d_ws;
  unsigned short* h1p = (unsigned short*)w;  w += align256((size_t)n * H1 * 2);  // bf16 [n][64]
  unsigned short* h2p = (unsigned short*)w;  w += align256((size_t)n * H2 * 2);  // bf16 [n][32]
  u32* csr2   = (u32*)w;   w += align256((size_t)E * 4);
  u32* packed = (u32*)w;   w += align256((size_t)E * 4);
  int* bh     = (int*)w;   w += align256(((size_t)L + 1) * 4);
  int* S      = (int*)w;   w += align256(((size_t)L + 1) * 4);
  int* deg    = (int*)w;   w += align256((size_t)n * 4);
  float* dinv = (float*)w; w += align256((size_t)n * 4);
  int* off    = (int*)w;   w += align256(((size_t)n + 1) * 4);

  int gw8 = (n + 7) / 8;  // 8 nodes per 256-thread block (2 per wave)
  int pblk = (n + 15) / 16;

  hipMemsetAsync(deg, 0, (size_t)n * 4, stream);
  k_hist2<<<BLK, 256, 0, stream>>>(dstp, bh, deg, E, EPB, NBk);
  k_scan_dinv<<<1 + (n + 1023) / 1024, 1024, 0, stream>>>(bh, S, deg, dinv, L, n);
  k_scat_proj<<<BLK + pblk, 256, 0, stream>>>(src, dstp, S, packed, E, EPB, NBk,
                                              (const float4*)x, W1, dinv, h1p, n);
  k_build3<<<NBk, 256, 0, stream>>>(packed, S, csr2, off, n, NBk);
  k_agg64_proj2<<<gw8, 256, 0, stream>>>((const u32*)h1p, dinv, off, (const int*)csr2,
                                         b1, W2, h2p, n);
  k_agg32_tree<<<gw8, 256, 0, stream>>>((const u32*)h2p, dinv, off, (const int*)csr2,
                                        b2, gw, gb, lw, out, n);
}

// Round 10
// 442.156 us; speedup vs baseline: 1.2620x; 1.2620x over previous
//
#include <hip/hip_runtime.h>
#include <math.h>

#define IN_DIM 128
#define H1 64
#define H2 32
#define NC 8
#define NB_MAX 512     // max buckets (n <= 131072)
#define BLK 512        // edge partition blocks
#define CAP 10240      // LDS staging capacity per bucket (entries; max bucket ~8.6K)

typedef unsigned int u32;

__device__ __forceinline__ float bf_lo(u32 u) { return __uint_as_float(u << 16); }
__device__ __forceinline__ float bf_hi(u32 u) { return __uint_as_float(u & 0xffff0000u); }
__device__ __forceinline__ unsigned short f2b(float f) {  // RNE float->bf16
  u32 u = __float_as_uint(f);
  u += 0x7fffu + ((u >> 16) & 1u);
  return (unsigned short)(u >> 16);
}

// ---------------- P1: per-block bucket histogram (LDS atomics only) ----------------
// bucket(d) = d >> 8 (256 nodes per bucket). (R9 lesson: NO per-node global
// atomics here — 3.2M random atomicAdds cost 130 us.)

__global__ __launch_bounds__(256) void k_hist(const int* __restrict__ dst,
                                              int* __restrict__ bh,
                                              int E, int EPB, int NBk) {
  __shared__ int h[NB_MAX];
  int k = blockIdx.x, tid = threadIdx.x;
  for (int i = tid; i < NBk; i += 256) h[i] = 0;
  __syncthreads();
  int st = k * EPB, en = min(E, st + EPB);
  for (int i = st + tid; i < en; i += 256)
    atomicAdd(&h[((u32)dst[i]) >> 8], 1);
  __syncthreads();
  for (int b = tid; b < NBk; b += 256) bh[b * BLK + k] = h[b];
}

// ---------------- P2 (R23): ONE monolithic scan kernel (replaces 3-kernel chain) ----------------
// Single 1024-thread block: exclusive scan of bh[L] -> S[L], S[L] = E.

__global__ __launch_bounds__(1024) void k_scan(const int* __restrict__ A,
                                               int* __restrict__ S, int L) {
  __shared__ int part[1024];
  int t = threadIdx.x;
  int C = (L + 1023) >> 10;        // per-thread chunk
  C = (C + 3) & ~3;                // multiple of 4 for int4
  int st = t * C, en = min(st + C, L);
  int s = 0;
  int i = st;
  for (; i + 3 < en; i += 4) {
    int4 v = *(const int4*)(A + i);
    s += v.x + v.y + v.z + v.w;
  }
  for (; i < en; ++i) s += A[i];
  part[t] = s;
  __syncthreads();
  for (int d = 1; d < 1024; d <<= 1) {
    int v = (t >= d) ? part[t - d] : 0;
    __syncthreads();
    part[t] += v;
    __syncthreads();
  }
  int base = (t == 0) ? 0 : part[t - 1];
  i = st;
  for (; i + 3 < en; i += 4) {
    int4 v = *(const int4*)(A + i);
    int4 o;
    o.x = base; o.y = base + v.x; o.z = o.y + v.y; o.w = o.z + v.z;
    *(int4*)(S + i) = o;
    base = o.w + v.w;
  }
  for (; i < en; ++i) { S[i] = base; base += A[i]; }
  if (t == 1023) S[L] = part[1023];
}

// ---------------- P3: bucket scatter (LDS cursors, disjoint global ranges) ----------------
// packed entry: bits[0,17) = src, bits[17,25) = local node id within bucket.

__global__ __launch_bounds__(256) void k_scatter(const int* __restrict__ src,
                                                 const int* __restrict__ dst,
                                                 const int* __restrict__ S,
                                                 u32* __restrict__ packed,
                                                 int E, int EPB, int NBk) {
  __shared__ int cur[NB_MAX];
  int k = blockIdx.x, tid = threadIdx.x;
  for (int b = tid; b < NBk; b += 256) cur[b] = S[b * BLK + k];
  __syncthreads();
  int st = k * EPB, en = min(E, st + EPB);
  for (int i = st + tid; i < en; i += 256) {
    int d = dst[i];
    int b = ((u32)d) >> 8;
    int pos = atomicAdd(&cur[b], 1);
    packed[pos] = (((u32)d & 255u) << 17) | (u32)src[i];
  }
}

// ---------------- P4 (R21): per-bucket sort by (dst_local, src-tile) + off + dinv ----------------
// key = dl*8 | (src>>14): node segments contiguous (CSR via off[n+1]) and
// coarse-ascending in src (8 tiles) => agg kernels see a src-ordered stream
// (R8: FETCH 157 -> ~148e3 KB for free).

__global__ __launch_bounds__(256) void k_build3(const u32* __restrict__ packed,
                                                const int* __restrict__ S,
                                                u32* __restrict__ csr2,
                                                int* __restrict__ off,
                                                float* __restrict__ dinv,
                                                int n, int NBk) {
  __shared__ int bins[2048];
  __shared__ int cur[2048];
  __shared__ int scn[256];
  __shared__ u32 sbuf[CAP];  // 40 KB staging
  int b = blockIdx.x, tid = threadIdx.x;
  int r0 = S[b * BLK];
  int r1 = S[(b + 1) * BLK];  // last bucket: S[L] = E
  int m = r1 - r0;
  for (int i = tid; i < 2048; i += 256) bins[i] = 0;
  __syncthreads();
  for (int i = r0 + tid; i < r1; i += 256) {
    u32 p = packed[i];
    int key = (int)((p >> 17) << 3) | (int)((p & 0x1FFFFu) >> 14);
    atomicAdd(&bins[key], 1);
  }
  __syncthreads();
  int s = 0;
#pragma unroll
  for (int u = 0; u < 8; ++u) s += bins[tid * 8 + u];  // s = degree of dl=tid
  scn[tid] = s;
  __syncthreads();
  for (int d = 1; d < 256; d <<= 1) {
    int t = (tid >= d) ? scn[tid - d] : 0;
    __syncthreads();
    scn[tid] += t;
    __syncthreads();
  }
  int base = scn[tid] - s;  // exclusive start of dl=tid's 8 bins
  int node = b * 256 + tid;
  if (node < n) {
    off[node] = r0 + base;
    dinv[node] = rsqrtf((float)(s + 1));  // +1 self-loop
  }
  if (b == NBk - 1 && tid == 0) off[n] = r1;
#pragma unroll
  for (int u = 0; u < 8; ++u) {
    int k = tid * 8 + u;
    cur[k] = base;
    base += bins[k];
  }
  __syncthreads();
  if (m <= CAP) {
    for (int i = r0 + tid; i < r1; i += 256) {
      u32 p = packed[i];
      int key = (int)((p >> 17) << 3) | (int)((p & 0x1FFFFu) >> 14);
      int pos = atomicAdd(&cur[key], 1);
      sbuf[pos] = p & 0x1FFFFu;
    }
    __syncthreads();
    for (int j = tid; j < m; j += 256)
      csr2[r0 + j] = sbuf[j];
  } else {
    for (int i = r0 + tid; i < r1; i += 256) {
      u32 p = packed[i];
      int key = (int)((p >> 17) << 3) | (int)((p & 0x1FFFFu) >> 14);
      int pos = atomicAdd(&cur[key], 1);
      csr2[r0 + pos] = p & 0x1FFFFu;
    }
  }
}

// ---------------- projection 1: h1p = bf16(dinv * (x @ W1^T))  [n,128]->[n,64] ----------------

__global__ void k_proj1(const float4* __restrict__ x4, const float* __restrict__ W1,
                        const float* __restrict__ dinv,
                        unsigned short* __restrict__ h1p, int n) {
  __shared__ float xs[16][IN_DIM];
  __shared__ float wt[IN_DIM][H1 + 1];
  int tid = threadIdx.x;
  int row0 = blockIdx.x * 16;

  for (int i = tid; i < (H1 * IN_DIM / 4); i += 256) {
    float4 w = ((const float4*)W1)[i];
    int o = (i * 4) / IN_DIM;
    int k = (i * 4) % IN_DIM;
    wt[k + 0][o] = w.x; wt[k + 1][o] = w.y; wt[k + 2][o] = w.z; wt[k + 3][o] = w.w;
  }
  for (int i = tid; i < 16 * IN_DIM / 4; i += 256) {
    int r = (i * 4) / IN_DIM, k = (i * 4) % IN_DIM;
    int row = row0 + r;
    if (row < n)
      *((float4*)&xs[r][k]) = x4[(size_t)row * (IN_DIM / 4) + k / 4];
  }
  __syncthreads();

  int o = tid & 63, rq = tid >> 6;
  float a0 = 0.f, a1 = 0.f, a2 = 0.f, a3 = 0.f;
  for (int k = 0; k < IN_DIM; ++k) {
    float w = wt[k][o];
    a0 += xs[rq * 4 + 0][k] * w;
    a1 += xs[rq * 4 + 1][k] * w;
    a2 += xs[rq * 4 + 2][k] * w;
    a3 += xs[rq * 4 + 3][k] * w;
  }
  int r = row0 + rq * 4;
  if (r + 0 < n) h1p[(size_t)(r + 0) * H1 + o] = f2b(a0 * dinv[r + 0]);
  if (r + 1 < n) h1p[(size_t)(r + 1) * H1 + o] = f2b(a1 * dinv[r + 1]);
  if (r + 2 < n) h1p[(size_t)(r + 2) * H1 + o] = f2b(a2 * dinv[r + 2]);
  if (r + 3 < n) h1p[(size_t)(r + 3) * H1 + o] = f2b(a3 * dinv[r + 3]);
}

// ---------------- fused: layer-1 gather-agg + bias + relu + proj2 (R18/R5 best) ----------------
// TWO independent nodes per wave; one csr load carries 16 ids per node; each of
// the 4 gather instrs carries 4 edges of node0 + 4 of node1.

#define ACC8(v) do { \
    a0 += bf_lo((v).x); a1 += bf_hi((v).x); \
    a2 += bf_lo((v).y); a3 += bf_hi((v).y); \
    a4 += bf_lo((v).z); a5 += bf_hi((v).z); \
    a6 += bf_lo((v).w); a7 += bf_hi((v).w); } while (0)

#define RED8(m) do { \
    a0 += __shfl_xor(a0, m, 64); a1 += __shfl_xor(a1, m, 64); \
    a2 += __shfl_xor(a2, m, 64); a3 += __shfl_xor(a3, m, 64); \
    a4 += __shfl_xor(a4, m, 64); a5 += __shfl_xor(a5, m, 64); \
    a6 += __shfl_xor(a6, m, 64); a7 += __shfl_xor(a7, m, 64); } while (0)

__global__ __launch_bounds__(256) void k_agg64_proj2(
    const u32* __restrict__ hp,    // [n][32] packed bf16x2 (= [n][8] uint4)
    const float* __restrict__ dinv,
    const int* __restrict__ off, const int* __restrict__ csr,
    const float* __restrict__ b1, const float* __restrict__ W2,
    unsigned short* __restrict__ h2p, int n) {
  __shared__ float wt[H1][H2 + 1];   // W2 transposed: wt[k][o]
  __shared__ float rows[4][2][H1];   // relu(out1) rows, 2 nodes per wave
  __shared__ float b1s[H1];
  int tid = threadIdx.x;

  for (int i = tid; i < H2 * H1 / 4; i += 256) {
    float4 w = ((const float4*)W2)[i];
    int o = (i * 4) / H1, k = (i * 4) % H1;
    wt[k + 0][o] = w.x; wt[k + 1][o] = w.y; wt[k + 2][o] = w.z; wt[k + 3][o] = w.w;
  }
  if (tid < 16) ((float4*)b1s)[tid] = ((const float4*)b1)[tid];
  __syncthreads();

  int lane = tid & 63;
  int wv = __builtin_amdgcn_readfirstlane(tid >> 6);
  int p0n = (blockIdx.x * 4 + wv) * 2;       // first of this wave's 2 nodes
  int p0c = min(p0n, n - 1);
  int p1c = min(p0n + 1, n - 1);
  int g = lane >> 3, j = lane & 7;           // 8 groups of 8 lanes; lane j reads 16B
  int nh = g >> 2;                           // node-half of this group

  int tt = 0;
  if (lane < 3) tt = off[min(p0n + lane, n)];
  int r00 = __shfl(tt, 0, 64);
  int r01 = __shfl(tt, 1, 64);
  int r11 = __shfl(tt, 2, 64);
  float dv = 0.f;
  if (lane < 2) dv = dinv[min(p0n + lane, n - 1)];
  float d0 = __shfl(dv, 0, 64), d1 = __shfl(dv, 1, 64);

  const uint4* __restrict__ hp4 = (const uint4*)hp;
  float a0 = 0.f, a1 = 0.f, a2 = 0.f, a3 = 0.f,
        a4 = 0.f, a5 = 0.f, a6 = 0.f, a7 = 0.f;

  if ((g & 3) == 0) {  // self terms: group 0 -> node0, group 4 -> node1
    uint4 v = hp4[(size_t)(nh ? p1c : p0c) * (H1 / 8) + j];
    ACC8(v);
  }

  int mx = max(r01 - r00, r11 - r01);
  for (int kk = 0; kk * 16 < mx; ++kk) {
    int b0 = r00 + 16 * kk, b1e = r01 + 16 * kk;
    int ci = (lane < 32) ? min(b0 + (lane & 15), r01 - 1)
                         : min(b1e + (lane & 15), r11 - 1);
    int s = csr[max(ci, 0)];     // 16 ids per node, clamped coalesced load
#pragma unroll
    for (int it = 0; it < 4; ++it) {
      int e = it * 4 + (g & 3);
      int sv = __shfl(s, (nh ? 32 : 0) + e, 64);
      int eidx = (nh ? b1e : b0) + e;
      int lim = nh ? r11 : r01;
      if (eidx < lim) {
        uint4 v = hp4[(size_t)sv * (H1 / 8) + j];   // 4+4 edges / instruction
        ACC8(v);
      }
    }
  }
  RED8(8); RED8(16);  // reduce across the 4 groups of each node-half

  float d = (lane < 32) ? d0 : d1;
  if ((lane & 31) < 8) {   // lane j holds cols [8j, 8j+8) of its node
    int jj = lane & 7, nn = lane >> 5;
    float4 v0, v1;
    v0.x = fmaxf(a0 * d + b1s[8 * jj + 0], 0.f);
    v0.y = fmaxf(a1 * d + b1s[8 * jj + 1], 0.f);
    v0.z = fmaxf(a2 * d + b1s[8 * jj + 2], 0.f);
    v0.w = fmaxf(a3 * d + b1s[8 * jj + 3], 0.f);
    v1.x = fmaxf(a4 * d + b1s[8 * jj + 4], 0.f);
    v1.y = fmaxf(a5 * d + b1s[8 * jj + 5], 0.f);
    v1.z = fmaxf(a6 * d + b1s[8 * jj + 6], 0.f);
    v1.w = fmaxf(a7 * d + b1s[8 * jj + 7], 0.f);
    *(float4*)&rows[wv][nn][8 * jj + 0] = v0;
    *(float4*)&rows[wv][nn][8 * jj + 4] = v1;
  }
  __syncthreads();

  // proj2: lane -> (node = lane>>5, o = lane&31); full k loop, no final shfl
  int node = lane >> 5, o = lane & 31;
  float a = 0.f;
#pragma unroll
  for (int k = 0; k < H1; ++k) a += rows[wv][node][k] * wt[k][o];
  int wout = p0n + node;
  if (wout < n) h2p[(size_t)wout * H2 + o] = f2b(a * ((node) ? d1 : d0));
}

// ---------------- fused: layer-2 gather-agg + b2 + gates + leaf (R18/R5 best) ----------------

__global__ __launch_bounds__(256) void k_agg32_tree(
    const u32* __restrict__ hp,    // [n][16] packed bf16x2 (= [n][4] uint4)
    const float* __restrict__ dinv,
    const int* __restrict__ off, const int* __restrict__ csr,
    const float* __restrict__ b2, const float* __restrict__ gate_w,
    const float* __restrict__ gate_b, const float* __restrict__ leaf_w,
    float* __restrict__ out, int n) {
  __shared__ float gwt[H2][H2 + 1];  // gate_w transposed: gwt[k][j]
  __shared__ float lws[H2][NC + 1];
  __shared__ float rowh[4][2][H2];
  __shared__ float rowg[4][2][H2];
  __shared__ float b2s[H2];
  int tid = threadIdx.x;

  {
    float4 w = ((const float4*)gate_w)[tid];  // H2*H2/4 == 256
    int jj = (tid * 4) / H2, k = (tid * 4) % H2;
    gwt[k + 0][jj] = w.x; gwt[k + 1][jj] = w.y; gwt[k + 2][jj] = w.z; gwt[k + 3][jj] = w.w;
  }
  lws[tid >> 3][tid & 7] = leaf_w[tid];  // H2*NC == 256
  if (tid < 8) ((float4*)b2s)[tid] = ((const float4*)b2)[tid];
  __syncthreads();

  int lane = tid & 63;
  int wv = __builtin_amdgcn_readfirstlane(tid >> 6);
  int p0n = (blockIdx.x * 4 + wv) * 2;
  int p0c = min(p0n, n - 1);
  int p1c = min(p0n + 1, n - 1);
  int g = lane >> 2, j = lane & 3;   // 16 groups of 4 lanes
  int nh = g >> 3;                   // node-half of this group

  int tt = 0;
  if (lane < 3) tt = off[min(p0n + lane, n)];
  int r00 = __shfl(tt, 0, 64);
  int r01 = __shfl(tt, 1, 64);
  int r11 = __shfl(tt, 2, 64);
  float dv = 0.f;
  if (lane < 2) dv = dinv[min(p0n + lane, n - 1)];
  float d0 = __shfl(dv, 0, 64), d1 = __shfl(dv, 1, 64);

  const uint4* __restrict__ hp4 = (const uint4*)hp;
  float a0 = 0.f, a1 = 0.f, a2 = 0.f, a3 = 0.f,
        a4 = 0.f, a5 = 0.f, a6 = 0.f, a7 = 0.f;

  if ((g & 7) == 0) {  // self terms: group 0 -> node0, group 8 -> node1
    uint4 v = hp4[(size_t)(nh ? p1c : p0c) * (H2 / 8) + j];
    ACC8(v);
  }

  int mx = max(r01 - r00, r11 - r01);
  for (int kk = 0; kk * 16 < mx; ++kk) {
    int b0 = r00 + 16 * kk, b1e = r01 + 16 * kk;
    int ci = (lane < 32) ? min(b0 + (lane & 15), r01 - 1)
                         : min(b1e + (lane & 15), r11 - 1);
    int s = csr[max(ci, 0)];
#pragma unroll
    for (int it = 0; it < 2; ++it) {
      int e = it * 8 + (g & 7);
      int sv = __shfl(s, (nh ? 32 : 0) + e, 64);
      int eidx = (nh ? b1e : b0) + e;
      int lim = nh ? r11 : r01;
      if (eidx < lim) {
        uint4 v = hp4[(size_t)sv * (H2 / 8) + j];   // 8+8 edges / instruction
        ACC8(v);
      }
    }
  }
  RED8(4); RED8(8); RED8(16);  // reduce across the 8 groups of each node-half

  float d = (lane < 32) ? d0 : d1;
  if ((lane & 31) < 4) {   // lane j holds cols [8j, 8j+8) of its node
    int jj = lane & 3, nn = lane >> 5;
    float4 v0, v1;
    v0.x = a0 * d + b2s[8 * jj + 0];
    v0.y = a1 * d + b2s[8 * jj + 1];
    v0.z = a2 * d + b2s[8 * jj + 2];
    v0.w = a3 * d + b2s[8 * jj + 3];
    v1.x = a4 * d + b2s[8 * jj + 4];
    v1.y = a5 * d + b2s[8 * jj + 5];
    v1.z = a6 * d + b2s[8 * jj + 6];
    v1.w = a7 * d + b2s[8 * jj + 7];
    *(float4*)&rowh[wv][nn][8 * jj + 0] = v0;
    *(float4*)&rowh[wv][nn][8 * jj + 4] = v1;
  }
  __syncthreads();

  // gates: lane -> (node = lane>>5, f = lane&31); full k loop
  int node = lane >> 5, f = lane & 31;
  float gacc = 0.f;
#pragma unroll
  for (int k = 0; k < H2; ++k) gacc += rowh[wv][node][k] * gwt[k][f];
  rowg[wv][node][f] = 1.0f / (1.0f + __expf(-(gacc + gate_b[f])));
  __syncthreads();

  // leaf: within each 32-half, 4 groups of 8 lanes partial-sum then xor-reduce
  int c = lane & 7, gi = (lane >> 3) & 3;
  float a = 0.f;
#pragma unroll
  for (int j8 = 0; j8 < 8; ++j8) {
    int jj = gi * 8 + j8;
    a += rowg[wv][node][jj] * lws[jj][c];
  }
  a += __shfl_xor(a, 8, 64);
  a += __shfl_xor(a, 16, 64);
  int wout = p0n + node;
  if ((lane & 31) < 8 && wout < n) out[(size_t)wout * NC + c] = a;
}

// ---------------- host ----------------

static inline size_t align256(size_t x) { return (x + 255) & ~(size_t)255; }

extern "C" void kernel_launch(void* const* d_in, const int* in_sizes, int n_in,
                              void* d_out, int out_size, void* d_ws, size_t ws_size,
                              hipStream_t stream) {
  const float* x  = (const float*)d_in[0];
  const int*   ei = (const int*)d_in[1];
  const float* W1 = (const float*)d_in[2];
  const float* b1 = (const float*)d_in[3];
  const float* W2 = (const float*)d_in[4];
  const float* b2 = (const float*)d_in[5];
  const float* gw = (const float*)d_in[6];
  const float* gb = (const float*)d_in[7];
  const float* lw = (const float*)d_in[8];
  float* out = (float*)d_out;

  int n = in_sizes[0] / IN_DIM;
  int E = in_sizes[1] / 2;
  const int* src  = ei;
  const int* dstp = ei + E;

  int NBk = (n + 255) >> 8;                    // buckets of 256 nodes
  int EPB = (E + BLK - 1) / BLK;               // edges per partition block
  int L   = NBk * BLK;                         // blockhist entries

  // workspace layout: hot gather tables FIRST (256B-aligned; R17 straddle fix)
  char* w = (char*)d_ws;
  unsigned short* h1p = (unsigned short*)w;  w += align256((size_t)n * H1 * 2);  // bf16 [n][64]
  unsigned short* h2p = (unsigned short*)w;  w += align256((size_t)n * H2 * 2);  // bf16 [n][32]
  u32* csr2   = (u32*)w;   w += align256((size_t)E * 4);
  u32* packed = (u32*)w;   w += align256((size_t)E * 4);
  int* bh     = (int*)w;   w += align256(((size_t)L + 1) * 4);
  int* S      = (int*)w;   w += align256(((size_t)L + 1) * 4);
  float* dinv = (float*)w; w += align256((size_t)n * 4);
  int* off    = (int*)w;   w += align256(((size_t)n + 1) * 4);

  int gw8 = (n + 7) / 8;  // 8 nodes per 256-thread block (2 per wave)

  k_hist<<<BLK, 256, 0, stream>>>(dstp, bh, E, EPB, NBk);
  k_scan<<<1, 1024, 0, stream>>>(bh, S, L);
  k_scatter<<<BLK, 256, 0, stream>>>(src, dstp, S, packed, E, EPB, NBk);
  k_build3<<<NBk, 256, 0, stream>>>(packed, S, csr2, off, dinv, n, NBk);
  k_proj1<<<(n + 15) / 16, 256, 0, stream>>>((const float4*)x, W1, dinv, h1p, n);
  k_agg64_proj2<<<gw8, 256, 0, stream>>>((const u32*)h1p, dinv, off, (const int*)csr2,
                                         b1, W2, h2p, n);
  k_agg32_tree<<<gw8, 256, 0, stream>>>((const u32*)h2p, dinv, off, (const int*)csr2,
                                        b2, gw, gb, lw, out, n);
}

// Round 11
// 359.549 us; speedup vs baseline: 1.5519x; 1.2298x over previous
//
#include <hip/hip_runtime.h>
#include <math.h>

#define IN_DIM 128
#define H1 64
#define H2 32
#define NC 8
#define SCAN_CH 1024   // elements per scan block (256 threads x 4)
#define NB_MAX 512     // max buckets (n <= 131072)
#define BLK 512        // edge partition blocks
#define CAP 10240      // LDS staging capacity per bucket (entries; max bucket ~8.6K)

typedef unsigned int u32;

__device__ __forceinline__ float bf_lo(u32 u) { return __uint_as_float(u << 16); }
__device__ __forceinline__ float bf_hi(u32 u) { return __uint_as_float(u & 0xffff0000u); }
__device__ __forceinline__ unsigned short f2b(float f) {  // RNE float->bf16
  u32 u = __float_as_uint(f);
  u += 0x7fffu + ((u >> 16) & 1u);
  return (unsigned short)(u >> 16);
}

// ---------------- P1: per-block bucket histogram (LDS atomics only) ----------------
// bucket(d) = d >> 8. (R9: no per-node global atomics — 130 us. R10: no
// single-block monolithic scan — 102 us.)

__global__ __launch_bounds__(256) void k_hist(const int* __restrict__ dst,
                                              int* __restrict__ bh,
                                              int E, int EPB, int NBk) {
  __shared__ int h[NB_MAX];
  int k = blockIdx.x, tid = threadIdx.x;
  for (int i = tid; i < NBk; i += 256) h[i] = 0;
  __syncthreads();
  int st = k * EPB, en = min(E, st + EPB);
  for (int i = st + tid; i < en; i += 256)
    atomicAdd(&h[((u32)dst[i]) >> 8], 1);
  __syncthreads();
  for (int b = tid; b < NBk; b += 256) bh[b * BLK + k] = h[b];
}

// ---- generic 3-phase exclusive scan of A[L] -> S[L], S[L] = total (proven chain) ----

__global__ __launch_bounds__(256) void k_gsc1(const int* __restrict__ A,
                                              int* __restrict__ bsum, int L) {
  int b = blockIdx.x, tid = threadIdx.x;
  int i0 = b * SCAN_CH + tid * 4;
  int s = 0;
  if (i0 + 3 < L) {
    int4 v = *(const int4*)(A + i0);
    s = v.x + v.y + v.z + v.w;
  } else {
    for (int i = i0; i < L; ++i) s += A[i];
  }
  __shared__ int red[256];
  red[tid] = s;
  __syncthreads();
  for (int d = 128; d > 0; d >>= 1) {
    if (tid < d) red[tid] += red[tid + d];
    __syncthreads();
  }
  if (tid == 0) bsum[b] = red[0];
}

__global__ __launch_bounds__(256) void k_gsc2(const int* __restrict__ bsum,
                                              int* __restrict__ bbase,
                                              int* __restrict__ S, int nbk, int L) {
  __shared__ int part[256];
  int tid = threadIdx.x;
  int chunk = (nbk + 255) / 256;
  int st = tid * chunk, en = min(st + chunk, nbk);
  int s = 0;
  for (int i = st; i < en; ++i) s += bsum[i];
  part[tid] = s;
  __syncthreads();
  for (int d = 1; d < 256; d <<= 1) {
    int t = (tid >= d) ? part[tid - d] : 0;
    __syncthreads();
    part[tid] += t;
    __syncthreads();
  }
  int base = (tid == 0) ? 0 : part[tid - 1];
  for (int i = st; i < en; ++i) { bbase[i] = base; base += bsum[i]; }
  if (tid == 255) S[L] = part[255];
}

__global__ __launch_bounds__(256) void k_gsc3(const int* __restrict__ A,
                                              const int* __restrict__ bbase,
                                              int* __restrict__ S, int L) {
  int b = blockIdx.x, tid = threadIdx.x;
  int i0 = b * SCAN_CH + tid * 4;
  int e0 = 0, e1 = 0, e2 = 0, e3 = 0;
  if (i0 + 3 < L) {
    int4 v = *(const int4*)(A + i0);
    e0 = v.x; e1 = v.y; e2 = v.z; e3 = v.w;
  } else {
    if (i0 + 0 < L) e0 = A[i0 + 0];
    if (i0 + 1 < L) e1 = A[i0 + 1];
    if (i0 + 2 < L) e2 = A[i0 + 2];
    if (i0 + 3 < L) e3 = A[i0 + 3];
  }
  __shared__ int part[256];
  part[tid] = e0 + e1 + e2 + e3;
  __syncthreads();
  for (int d = 1; d < 256; d <<= 1) {
    int t = (tid >= d) ? part[tid - d] : 0;
    __syncthreads();
    part[tid] += t;
    __syncthreads();
  }
  int base = bbase[b] + ((tid == 0) ? 0 : part[tid - 1]);
  int o0 = base, o1 = o0 + e0, o2 = o1 + e1, o3 = o2 + e2;
  if (i0 + 3 < L) {
    int4 o; o.x = o0; o.y = o1; o.z = o2; o.w = o3;
    *(int4*)(S + i0) = o;
  } else {
    if (i0 + 0 < L) S[i0 + 0] = o0;
    if (i0 + 1 < L) S[i0 + 1] = o1;
    if (i0 + 2 < L) S[i0 + 2] = o2;
    if (i0 + 3 < L) S[i0 + 3] = o3;
  }
}

// ---------------- P3: bucket scatter (LDS cursors, disjoint global ranges) ----------------

__global__ __launch_bounds__(256) void k_scatter(const int* __restrict__ src,
                                                 const int* __restrict__ dst,
                                                 const int* __restrict__ S,
                                                 u32* __restrict__ packed,
                                                 int E, int EPB, int NBk) {
  __shared__ int cur[NB_MAX];
  int k = blockIdx.x, tid = threadIdx.x;
  for (int b = tid; b < NBk; b += 256) cur[b] = S[b * BLK + k];
  __syncthreads();
  int st = k * EPB, en = min(E, st + EPB);
  for (int i = st + tid; i < en; i += 256) {
    int d = dst[i];
    int b = ((u32)d) >> 8;
    int pos = atomicAdd(&cur[b], 1);
    packed[pos] = (((u32)d & 255u) << 17) | (u32)src[i];
  }
}

// ---------------- P4 (R21): per-bucket sort by (dst_local, src-tile) + off + dinv ----------------
// key = dl*8 | (src>>14): node segments contiguous (CSR via off[n+1]) and
// coarse-ascending in src (R8: FETCH 157 -> ~148e3 KB for free).

__global__ __launch_bounds__(256) void k_build3(const u32* __restrict__ packed,
                                                const int* __restrict__ S,
                                                u32* __restrict__ csr2,
                                                int* __restrict__ off,
                                                float* __restrict__ dinv,
                                                int n, int NBk) {
  __shared__ int bins[2048];
  __shared__ int cur[2048];
  __shared__ int scn[256];
  __shared__ u32 sbuf[CAP];  // 40 KB staging
  int b = blockIdx.x, tid = threadIdx.x;
  int r0 = S[b * BLK];
  int r1 = S[(b + 1) * BLK];  // last bucket: S[L] = E
  int m = r1 - r0;
  for (int i = tid; i < 2048; i += 256) bins[i] = 0;
  __syncthreads();
  for (int i = r0 + tid; i < r1; i += 256) {
    u32 p = packed[i];
    int key = (int)((p >> 17) << 3) | (int)((p & 0x1FFFFu) >> 14);
    atomicAdd(&bins[key], 1);
  }
  __syncthreads();
  int s = 0;
#pragma unroll
  for (int u = 0; u < 8; ++u) s += bins[tid * 8 + u];  // s = degree of dl=tid
  scn[tid] = s;
  __syncthreads();
  for (int d = 1; d < 256; d <<= 1) {
    int t = (tid >= d) ? scn[tid - d] : 0;
    __syncthreads();
    scn[tid] += t;
    __syncthreads();
  }
  int base = scn[tid] - s;  // exclusive start of dl=tid's 8 bins
  int node = b * 256 + tid;
  if (node < n) {
    off[node] = r0 + base;
    dinv[node] = rsqrtf((float)(s + 1));  // +1 self-loop
  }
  if (b == NBk - 1 && tid == 0) off[n] = r1;
#pragma unroll
  for (int u = 0; u < 8; ++u) {
    int k = tid * 8 + u;
    cur[k] = base;
    base += bins[k];
  }
  __syncthreads();
  if (m <= CAP) {
    for (int i = r0 + tid; i < r1; i += 256) {
      u32 p = packed[i];
      int key = (int)((p >> 17) << 3) | (int)((p & 0x1FFFFu) >> 14);
      int pos = atomicAdd(&cur[key], 1);
      sbuf[pos] = p & 0x1FFFFu;
    }
    __syncthreads();
    for (int j = tid; j < m; j += 256)
      csr2[r0 + j] = sbuf[j];
  } else {
    for (int i = r0 + tid; i < r1; i += 256) {
      u32 p = packed[i];
      int key = (int)((p >> 17) << 3) | (int)((p & 0x1FFFFu) >> 14);
      int pos = atomicAdd(&cur[key], 1);
      csr2[r0 + pos] = p & 0x1FFFFu;
    }
  }
}

// ---------------- projection 1 (R24): h1p = bf16(dinv * (x @ W1^T)) ----------------
// k-step-4 inner loop: 4 float4 xs broadcasts + 4 scalar wt reads per 4 k
// (8 DS instrs vs 20) — proj1 was DS-issue-bound (5:4 DS:FMA ratio).

__global__ void k_proj1(const float4* __restrict__ x4, const float* __restrict__ W1,
                        const float* __restrict__ dinv,
                        unsigned short* __restrict__ h1p, int n) {
  __shared__ float xs[16][IN_DIM];
  __shared__ float wt[IN_DIM][H1 + 1];
  int tid = threadIdx.x;
  int row0 = blockIdx.x * 16;

  for (int i = tid; i < (H1 * IN_DIM / 4); i += 256) {
    float4 w = ((const float4*)W1)[i];
    int o = (i * 4) / IN_DIM;
    int k = (i * 4) % IN_DIM;
    wt[k + 0][o] = w.x; wt[k + 1][o] = w.y; wt[k + 2][o] = w.z; wt[k + 3][o] = w.w;
  }
  for (int i = tid; i < 16 * IN_DIM / 4; i += 256) {
    int r = (i * 4) / IN_DIM, k = (i * 4) % IN_DIM;
    int row = row0 + r;
    if (row < n)
      *((float4*)&xs[r][k]) = x4[(size_t)row * (IN_DIM / 4) + k / 4];
  }
  __syncthreads();

  int o = tid & 63, rq = tid >> 6;
  const float4* xr0 = (const float4*)&xs[rq * 4 + 0][0];
  const float4* xr1 = (const float4*)&xs[rq * 4 + 1][0];
  const float4* xr2 = (const float4*)&xs[rq * 4 + 2][0];
  const float4* xr3 = (const float4*)&xs[rq * 4 + 3][0];
  float a0 = 0.f, a1 = 0.f, a2 = 0.f, a3 = 0.f;
#pragma unroll 4
  for (int k4 = 0; k4 < IN_DIM / 4; ++k4) {
    float w0 = wt[4 * k4 + 0][o], w1 = wt[4 * k4 + 1][o],
          w2 = wt[4 * k4 + 2][o], w3 = wt[4 * k4 + 3][o];
    float4 v0 = xr0[k4], v1 = xr1[k4], v2 = xr2[k4], v3 = xr3[k4];
    a0 += v0.x * w0 + v0.y * w1 + v0.z * w2 + v0.w * w3;
    a1 += v1.x * w0 + v1.y * w1 + v1.z * w2 + v1.w * w3;
    a2 += v2.x * w0 + v2.y * w1 + v2.z * w2 + v2.w * w3;
    a3 += v3.x * w0 + v3.y * w1 + v3.z * w2 + v3.w * w3;
  }
  int r = row0 + rq * 4;
  if (r + 0 < n) h1p[(size_t)(r + 0) * H1 + o] = f2b(a0 * dinv[r + 0]);
  if (r + 1 < n) h1p[(size_t)(r + 1) * H1 + o] = f2b(a1 * dinv[r + 1]);
  if (r + 2 < n) h1p[(size_t)(r + 2) * H1 + o] = f2b(a2 * dinv[r + 2]);
  if (r + 3 < n) h1p[(size_t)(r + 3) * H1 + o] = f2b(a3 * dinv[r + 3]);
}

// ---------------- fused: layer-1 gather-agg + bias + relu + proj2 (R18/R5 best) ----------------

#define ACC8(v) do { \
    a0 += bf_lo((v).x); a1 += bf_hi((v).x); \
    a2 += bf_lo((v).y); a3 += bf_hi((v).y); \
    a4 += bf_lo((v).z); a5 += bf_hi((v).z); \
    a6 += bf_lo((v).w); a7 += bf_hi((v).w); } while (0)

#define RED8(m) do { \
    a0 += __shfl_xor(a0, m, 64); a1 += __shfl_xor(a1, m, 64); \
    a2 += __shfl_xor(a2, m, 64); a3 += __shfl_xor(a3, m, 64); \
    a4 += __shfl_xor(a4, m, 64); a5 += __shfl_xor(a5, m, 64); \
    a6 += __shfl_xor(a6, m, 64); a7 += __shfl_xor(a7, m, 64); } while (0)

__global__ __launch_bounds__(256) void k_agg64_proj2(
    const u32* __restrict__ hp,    // [n][32] packed bf16x2 (= [n][8] uint4)
    const float* __restrict__ dinv,
    const int* __restrict__ off, const int* __restrict__ csr,
    const float* __restrict__ b1, const float* __restrict__ W2,
    unsigned short* __restrict__ h2p, int n) {
  __shared__ float wt[H1][H2 + 1];   // W2 transposed: wt[k][o]
  __shared__ float rows[4][2][H1];   // relu(out1) rows, 2 nodes per wave
  __shared__ float b1s[H1];
  int tid = threadIdx.x;

  for (int i = tid; i < H2 * H1 / 4; i += 256) {
    float4 w = ((const float4*)W2)[i];
    int o = (i * 4) / H1, k = (i * 4) % H1;
    wt[k + 0][o] = w.x; wt[k + 1][o] = w.y; wt[k + 2][o] = w.z; wt[k + 3][o] = w.w;
  }
  if (tid < 16) ((float4*)b1s)[tid] = ((const float4*)b1)[tid];
  __syncthreads();

  int lane = tid & 63;
  int wv = __builtin_amdgcn_readfirstlane(tid >> 6);
  int p0n = (blockIdx.x * 4 + wv) * 2;       // first of this wave's 2 nodes
  int p0c = min(p0n, n - 1);
  int p1c = min(p0n + 1, n - 1);
  int g = lane >> 3, j = lane & 7;           // 8 groups of 8 lanes; lane j reads 16B
  int nh = g >> 2;                           // node-half of this group

  int tt = 0;
  if (lane < 3) tt = off[min(p0n + lane, n)];
  int r00 = __shfl(tt, 0, 64);
  int r01 = __shfl(tt, 1, 64);
  int r11 = __shfl(tt, 2, 64);
  float dv = 0.f;
  if (lane < 2) dv = dinv[min(p0n + lane, n - 1)];
  float d0 = __shfl(dv, 0, 64), d1 = __shfl(dv, 1, 64);

  const uint4* __restrict__ hp4 = (const uint4*)hp;
  float a0 = 0.f, a1 = 0.f, a2 = 0.f, a3 = 0.f,
        a4 = 0.f, a5 = 0.f, a6 = 0.f, a7 = 0.f;

  if ((g & 3) == 0) {  // self terms: group 0 -> node0, group 4 -> node1
    uint4 v = hp4[(size_t)(nh ? p1c : p0c) * (H1 / 8) + j];
    ACC8(v);
  }

  int mx = max(r01 - r00, r11 - r01);
  for (int kk = 0; kk * 16 < mx; ++kk) {
    int b0 = r00 + 16 * kk, b1e = r01 + 16 * kk;
    int ci = (lane < 32) ? min(b0 + (lane & 15), r01 - 1)
                         : min(b1e + (lane & 15), r11 - 1);
    int s = csr[max(ci, 0)];     // 16 ids per node, clamped coalesced load
#pragma unroll
    for (int it = 0; it < 4; ++it) {
      int e = it * 4 + (g & 3);
      int sv = __shfl(s, (nh ? 32 : 0) + e, 64);
      int eidx = (nh ? b1e : b0) + e;
      int lim = nh ? r11 : r01;
      if (eidx < lim) {
        uint4 v = hp4[(size_t)sv * (H1 / 8) + j];   // 4+4 edges / instruction
        ACC8(v);
      }
    }
  }
  RED8(8); RED8(16);  // reduce across the 4 groups of each node-half

  float d = (lane < 32) ? d0 : d1;
  if ((lane & 31) < 8) {   // lane j holds cols [8j, 8j+8) of its node
    int jj = lane & 7, nn = lane >> 5;
    float4 v0, v1;
    v0.x = fmaxf(a0 * d + b1s[8 * jj + 0], 0.f);
    v0.y = fmaxf(a1 * d + b1s[8 * jj + 1], 0.f);
    v0.z = fmaxf(a2 * d + b1s[8 * jj + 2], 0.f);
    v0.w = fmaxf(a3 * d + b1s[8 * jj + 3], 0.f);
    v1.x = fmaxf(a4 * d + b1s[8 * jj + 4], 0.f);
    v1.y = fmaxf(a5 * d + b1s[8 * jj + 5], 0.f);
    v1.z = fmaxf(a6 * d + b1s[8 * jj + 6], 0.f);
    v1.w = fmaxf(a7 * d + b1s[8 * jj + 7], 0.f);
    *(float4*)&rows[wv][nn][8 * jj + 0] = v0;
    *(float4*)&rows[wv][nn][8 * jj + 4] = v1;
  }
  __syncthreads();

  // proj2: lane -> (node = lane>>5, o = lane&31); full k loop, no final shfl
  int node = lane >> 5, o = lane & 31;
  float a = 0.f;
#pragma unroll
  for (int k = 0; k < H1; ++k) a += rows[wv][node][k] * wt[k][o];
  int wout = p0n + node;
  if (wout < n) h2p[(size_t)wout * H2 + o] = f2b(a * ((node) ? d1 : d0));
}

// ---------------- fused: layer-2 gather-agg + b2 + gates + leaf (R18/R5 best) ----------------

__global__ __launch_bounds__(256) void k_agg32_tree(
    const u32* __restrict__ hp,    // [n][16] packed bf16x2 (= [n][4] uint4)
    const float* __restrict__ dinv,
    const int* __restrict__ off, const int* __restrict__ csr,
    const float* __restrict__ b2, const float* __restrict__ gate_w,
    const float* __restrict__ gate_b, const float* __restrict__ leaf_w,
    float* __restrict__ out, int n) {
  __shared__ float gwt[H2][H2 + 1];  // gate_w transposed: gwt[k][j]
  __shared__ float lws[H2][NC + 1];
  __shared__ float rowh[4][2][H2];
  __shared__ float rowg[4][2][H2];
  __shared__ float b2s[H2];
  int tid = threadIdx.x;

  {
    float4 w = ((const float4*)gate_w)[tid];  // H2*H2/4 == 256
    int jj = (tid * 4) / H2, k = (tid * 4) % H2;
    gwt[k + 0][jj] = w.x; gwt[k + 1][jj] = w.y; gwt[k + 2][jj] = w.z; gwt[k + 3][jj] = w.w;
  }
  lws[tid >> 3][tid & 7] = leaf_w[tid];  // H2*NC == 256
  if (tid < 8) ((float4*)b2s)[tid] = ((const float4*)b2)[tid];
  __syncthreads();

  int lane = tid & 63;
  int wv = __builtin_amdgcn_readfirstlane(tid >> 6);
  int p0n = (blockIdx.x * 4 + wv) * 2;
  int p0c = min(p0n, n - 1);
  int p1c = min(p0n + 1, n - 1);
  int g = lane >> 2, j = lane & 3;   // 16 groups of 4 lanes
  int nh = g >> 3;                   // node-half of this group

  int tt = 0;
  if (lane < 3) tt = off[min(p0n + lane, n)];
  int r00 = __shfl(tt, 0, 64);
  int r01 = __shfl(tt, 1, 64);
  int r11 = __shfl(tt, 2, 64);
  float dv = 0.f;
  if (lane < 2) dv = dinv[min(p0n + lane, n - 1)];
  float d0 = __shfl(dv, 0, 64), d1 = __shfl(dv, 1, 64);

  const uint4* __restrict__ hp4 = (const uint4*)hp;
  float a0 = 0.f, a1 = 0.f, a2 = 0.f, a3 = 0.f,
        a4 = 0.f, a5 = 0.f, a6 = 0.f, a7 = 0.f;

  if ((g & 7) == 0) {  // self terms: group 0 -> node0, group 8 -> node1
    uint4 v = hp4[(size_t)(nh ? p1c : p0c) * (H2 / 8) + j];
    ACC8(v);
  }

  int mx = max(r01 - r00, r11 - r01);
  for (int kk = 0; kk * 16 < mx; ++kk) {
    int b0 = r00 + 16 * kk, b1e = r01 + 16 * kk;
    int ci = (lane < 32) ? min(b0 + (lane & 15), r01 - 1)
                         : min(b1e + (lane & 15), r11 - 1);
    int s = csr[max(ci, 0)];
#pragma unroll
    for (int it = 0; it < 2; ++it) {
      int e = it * 8 + (g & 7);
      int sv = __shfl(s, (nh ? 32 : 0) + e, 64);
      int eidx = (nh ? b1e : b0) + e;
      int lim = nh ? r11 : r01;
      if (eidx < lim) {
        uint4 v = hp4[(size_t)sv * (H2 / 8) + j];   // 8+8 edges / instruction
        ACC8(v);
      }
    }
  }
  RED8(4); RED8(8); RED8(16);  // reduce across the 8 groups of each node-half

  float d = (lane < 32) ? d0 : d1;
  if ((lane & 31) < 4) {   // lane j holds cols [8j, 8j+8) of its node
    int jj = lane & 3, nn = lane >> 5;
    float4 v0, v1;
    v0.x = a0 * d + b2s[8 * jj + 0];
    v0.y = a1 * d + b2s[8 * jj + 1];
    v0.z = a2 * d + b2s[8 * jj + 2];
    v0.w = a3 * d + b2s[8 * jj + 3];
    v1.x = a4 * d + b2s[8 * jj + 4];
    v1.y = a5 * d + b2s[8 * jj + 5];
    v1.z = a6 * d + b2s[8 * jj + 6];
    v1.w = a7 * d + b2s[8 * jj + 7];
    *(float4*)&rowh[wv][nn][8 * jj + 0] = v0;
    *(float4*)&rowh[wv][nn][8 * jj + 4] = v1;
  }
  __syncthreads();

  // gates: lane -> (node = lane>>5, f = lane&31); full k loop
  int node = lane >> 5, f = lane & 31;
  float gacc = 0.f;
#pragma unroll
  for (int k = 0; k < H2; ++k) gacc += rowh[wv][node][k] * gwt[k][f];
  rowg[wv][node][f] = 1.0f / (1.0f + __expf(-(gacc + gate_b[f])));
  __syncthreads();

  // leaf: within each 32-half, 4 groups of 8 lanes partial-sum then xor-reduce
  int c = lane & 7, gi = (lane >> 3) & 3;
  float a = 0.f;
#pragma unroll
  for (int j8 = 0; j8 < 8; ++j8) {
    int jj = gi * 8 + j8;
    a += rowg[wv][node][jj] * lws[jj][c];
  }
  a += __shfl_xor(a, 8, 64);
  a += __shfl_xor(a, 16, 64);
  int wout = p0n + node;
  if ((lane & 31) < 8 && wout < n) out[(size_t)wout * NC + c] = a;
}

// ---------------- host ----------------

static inline size_t align256(size_t x) { return (x + 255) & ~(size_t)255; }

extern "C" void kernel_launch(void* const* d_in, const int* in_sizes, int n_in,
                              void* d_out, int out_size, void* d_ws, size_t ws_size,
                              hipStream_t stream) {
  const float* x  = (const float*)d_in[0];
  const int*   ei = (const int*)d_in[1];
  const float* W1 = (const float*)d_in[2];
  const float* b1 = (const float*)d_in[3];
  const float* W2 = (const float*)d_in[4];
  const float* b2 = (const float*)d_in[5];
  const float* gw = (const float*)d_in[6];
  const float* gb = (const float*)d_in[7];
  const float* lw = (const float*)d_in[8];
  float* out = (float*)d_out;

  int n = in_sizes[0] / IN_DIM;
  int E = in_sizes[1] / 2;
  const int* src  = ei;
  const int* dstp = ei + E;

  int NBk = (n + 255) >> 8;                    // buckets of 256 nodes
  int EPB = (E + BLK - 1) / BLK;               // edges per partition block
  int L   = NBk * BLK;                         // blockhist entries
  int nbs = (L + SCAN_CH - 1) / SCAN_CH;       // scan blocks

  // workspace layout: hot gather tables FIRST (256B-aligned; R17 straddle fix)
  char* w = (char*)d_ws;
  unsigned short* h1p = (unsigned short*)w;  w += align256((size_t)n * H1 * 2);  // bf16 [n][64]
  unsigned short* h2p = (unsigned short*)w;  w += align256((size_t)n * H2 * 2);  // bf16 [n][32]
  u32* csr2   = (u32*)w;   w += align256((size_t)E * 4);
  u32* packed = (u32*)w;   w += align256((size_t)E * 4);
  int* bh     = (int*)w;   w += align256(((size_t)L + 1) * 4);
  int* S      = (int*)w;   w += align256(((size_t)L + 1) * 4);
  int* bsum   = (int*)w;   w += align256((size_t)nbs * 4);
  int* bbase  = (int*)w;   w += align256((size_t)nbs * 4);
  float* dinv = (float*)w; w += align256((size_t)n * 4);
  int* off    = (int*)w;   w += align256(((size_t)n + 1) * 4);

  int gw8 = (n + 7) / 8;  // 8 nodes per 256-thread block (2 per wave)

  k_hist<<<BLK, 256, 0, stream>>>(dstp, bh, E, EPB, NBk);
  k_gsc1<<<nbs, 256, 0, stream>>>(bh, bsum, L);
  k_gsc2<<<1, 256, 0, stream>>>(bsum, bbase, S, nbs, L);
  k_gsc3<<<nbs, 256, 0, stream>>>(bh, bbase, S, L);
  k_scatter<<<BLK, 256, 0, stream>>>(src, dstp, S, packed, E, EPB, NBk);
  k_build3<<<NBk, 256, 0, stream>>>(packed, S, csr2, off, dinv, n, NBk);
  k_proj1<<<(n + 15) / 16, 256, 0, stream>>>((const float4*)x, W1, dinv, h1p, n);
  k_agg64_proj2<<<gw8, 256, 0, stream>>>((const u32*)h1p, dinv, off, (const int*)csr2,
                                         b1, W2, h2p, n);
  k_agg32_tree<<<gw8, 256, 0, stream>>>((const u32*)h2p, dinv, off, (const int*)csr2,
                                        b2, gw, gb, lw, out, n);
}